// Round 1
// baseline (726.699 us; speedup 1.0000x reference)
//
#include <hip/hip_runtime.h>

// ---------------------------------------------------------------------------
// RoPE attention: out = softmax(mask(RoPE(xWq^T) @ RoPE(xWk^T)^T / sqrt(d))) @ (xWv^T)
// B=4, T=2048, d=1024. fp32 in/out, bf16 MFMA internally.
// Pipeline: cvt -> fused QKV GEMM (+RoPE epilogue, V stored transposed)
//           -> S GEMM (causal block skip) -> row softmax (in-place bf16 P)
//           -> PV GEMM (causal K truncation).
// ---------------------------------------------------------------------------

typedef float f32x4 __attribute__((ext_vector_type(4)));
typedef __bf16 bf16x8 __attribute__((ext_vector_type(8)));

#define BM 128
#define BN 128
#define BK 32

__device__ __forceinline__ unsigned short f2bf(float f) {
  union { float f; unsigned int u; } c; c.f = f;
  unsigned int u = c.u;
  u += 0x7fffu + ((u >> 16) & 1u);   // round-nearest-even
  return (unsigned short)(u >> 16);
}

__device__ __forceinline__ void async16(const void* gp, void* lp) {
  __builtin_amdgcn_global_load_lds(
      (const __attribute__((address_space(1))) void*)gp,
      (__attribute__((address_space(3))) void*)lp, 16, 0, 0);
}

// ---------------------------------------------------------------------------
__global__ __launch_bounds__(256) void cvt_bf16(const float4* __restrict__ in,
                                                ushort4* __restrict__ out, int n4) {
  int i = blockIdx.x * 256 + threadIdx.x;
  if (i >= n4) return;
  float4 v = in[i];
  ushort4 o;
  o.x = f2bf(v.x); o.y = f2bf(v.y); o.z = f2bf(v.z); o.w = f2bf(v.w);
  out[i] = o;
}

// ---------------------------------------------------------------------------
// NT GEMM: C[m,n] = sum_k A[m,k]*B[n,k]. 128x128 tile, BK=32, 4 waves (2x2),
// each wave 64x64 via 4x4 frags of mfma_f32_16x16x32_bf16.
// MODE 0: A=xb[8192x1024], B=Wb[3072x1024]; epilogue RoPE->Qr/Kr, V->Vt transposed.
// MODE 1: S = Qr@Kr^T per batch (z), skip blocks bn>bm+1. C fp32 ld 2048.
// MODE 2: out = P@Vt^T per batch (z), K truncated causally. A=P (bf16, lda 4096).
template <int MODE>
__global__ __launch_bounds__(256) void gemm_nt(
    const unsigned short* __restrict__ Abase,
    const unsigned short* __restrict__ Bbase,
    float* __restrict__ Cbase,
    unsigned short* __restrict__ Qr, unsigned short* __restrict__ Kr,
    unsigned short* __restrict__ Vt,
    int lda, int ldb, int ldc, int Kdim, int b0) {
  __shared__ __align__(16) unsigned short As[BM * BK];
  __shared__ __align__(16) unsigned short Bs[BN * BK];

  const int tid = threadIdx.x;
  const int lane = tid & 63;
  const int wave = tid >> 6;
  const int bn = blockIdx.x;
  const int bm = blockIdx.y;
  const int z = blockIdx.z;

  const unsigned short* A = Abase;
  const unsigned short* B = Bbase;
  float* C = Cbase;
  int ktiles = Kdim / BK;

  if (MODE == 1) {
    if (bn > bm + 1) return;  // fully masked under tril(k=1)
    A += (long)(b0 + z) * 2048 * 1024;
    B += (long)(b0 + z) * 2048 * 1024;
    C += (long)z * 2048 * 2048;  // chunk-local S buffer
  } else if (MODE == 2) {
    A += (long)z * 2048 * 4096;          // P rows stride 4096 bf16 (in-place in S)
    B += (long)(b0 + z) * 1024 * 2048;   // Vt[b][c][t]
    C += (long)(b0 + z) * 2048 * 1024;
    int kt = (bm * BM + BM + 1 + BK - 1) / BK;  // keys valid up to q+1
    if (kt < ktiles) ktiles = kt;
  }

  const int m0 = bm * BM;
  const int n0 = bn * BN;
  const int wm = (wave >> 1) * 64;
  const int wn = (wave & 1) * 64;

  f32x4 acc[4][4];
#pragma unroll
  for (int i = 0; i < 4; ++i)
#pragma unroll
    for (int j = 0; j < 4; ++j) acc[i][j] = (f32x4)(0.f);

  for (int kt = 0; kt < ktiles; ++kt) {
    const int k0 = kt * BK;
    __syncthreads();  // prior ds_reads done before LDS overwrite
#pragma unroll
    for (int p = 0; p < 2; ++p) {
      int f = p * 256 + tid;        // 512 x 16B covers one 128x32 bf16 tile
      int row = f >> 2;
      int kq = (f & 3) << 3;
      async16(A + (long)(m0 + row) * lda + k0 + kq, As + f * 8);
      async16(B + (long)(n0 + row) * ldb + k0 + kq, Bs + f * 8);
    }
    __syncthreads();  // drains vmcnt(0): LDS tiles ready

    bf16x8 af[4], bfr[4];
    const int kq = (lane >> 4) << 3;
#pragma unroll
    for (int i = 0; i < 4; ++i) {
      int m = wm + i * 16 + (lane & 15);
      af[i] = *(const bf16x8*)&As[m * BK + kq];
    }
#pragma unroll
    for (int j = 0; j < 4; ++j) {
      int n = wn + j * 16 + (lane & 15);
      bfr[j] = *(const bf16x8*)&Bs[n * BK + kq];
    }
#pragma unroll
    for (int i = 0; i < 4; ++i)
#pragma unroll
      for (int j = 0; j < 4; ++j)
        acc[i][j] = __builtin_amdgcn_mfma_f32_16x16x32_bf16(af[i], bfr[j], acc[i][j], 0, 0, 0);
  }

  // ---- epilogue ----
  if (MODE == 0) {
    const float NEG_L2_1E4_OVER_1024 = -13.287712379549449f / 1024.f;
#pragma unroll
    for (int j = 0; j < 4; ++j) {
      int gn = n0 + wn + j * 16 + (lane & 15);
      if (gn < 2048) {
        // Q or K slice: apply RoPE. Pair (2i,2i+1) lives in adjacent lanes.
        unsigned short* dst = (gn < 1024) ? Qr : Kr;
        int c = gn & 1023;
        float th = exp2f((float)(c & ~1) * NEG_L2_1E4_OVER_1024);
        float sgn = (gn & 1) ? 1.f : -1.f;
#pragma unroll
        for (int i = 0; i < 4; ++i) {
          int gmB = m0 + wm + i * 16 + ((lane >> 4) << 2);
#pragma unroll
          for (int r = 0; r < 4; ++r) {
            int gm = gmB + r;
            int t = gm & 2047;
            float v = acc[i][j][r];
            float p = __shfl_xor(v, 1);
            float s, cs;
            sincosf((float)t * th, &s, &cs);
            dst[(long)gm * 1024 + c] = f2bf(v * cs + sgn * p * s);
          }
        }
      } else {
        // V slice: store transposed Vt[b][c][t], 4 consecutive t per lane -> 8B store
        int c = gn - 2048;
#pragma unroll
        for (int i = 0; i < 4; ++i) {
          int gmB = m0 + wm + i * 16 + ((lane >> 4) << 2);
          int b = gmB >> 11, t = gmB & 2047;
          ushort4 pk;
          pk.x = f2bf(acc[i][j][0]);
          pk.y = f2bf(acc[i][j][1]);
          pk.z = f2bf(acc[i][j][2]);
          pk.w = f2bf(acc[i][j][3]);
          *(ushort4*)&Vt[((long)b * 1024 + c) * 2048 + t] = pk;
        }
      }
    }
  } else {
#pragma unroll
    for (int i = 0; i < 4; ++i) {
      int gmB = m0 + wm + i * 16 + ((lane >> 4) << 2);
#pragma unroll
      for (int j = 0; j < 4; ++j) {
        int gn = n0 + wn + j * 16 + (lane & 15);
#pragma unroll
        for (int r = 0; r < 4; ++r) C[(long)(gmB + r) * ldc + gn] = acc[i][j][r];
      }
    }
  }
}

// ---------------------------------------------------------------------------
// Row softmax over S (fp32, ld 2048), causal mask k <= q+1, scale 1/32,
// writes bf16 P in place at the row start (reads complete before writes:
// the two reduction barriers order them).
__global__ __launch_bounds__(256) void softmax_rows(float* __restrict__ S) {
  const long r = blockIdx.x;
  const int q = (int)(r & 2047);
  float* row = S + r * 2048;
  const int tid = threadIdx.x;

  float4 v0 = ((const float4*)row)[tid * 2];
  float4 v1 = ((const float4*)row)[tid * 2 + 1];
  float x[8] = {v0.x, v0.y, v0.z, v0.w, v1.x, v1.y, v1.z, v1.w};
  const int kb = tid * 8;
  float m = -1e30f;
#pragma unroll
  for (int j = 0; j < 8; ++j) {
    x[j] = (kb + j <= q + 1) ? x[j] * 0.03125f : -1e30f;
    m = fmaxf(m, x[j]);
  }
#pragma unroll
  for (int off = 32; off; off >>= 1) m = fmaxf(m, __shfl_xor(m, off));
  __shared__ float redm[4], reds[4];
  if ((tid & 63) == 0) redm[tid >> 6] = m;
  __syncthreads();
  m = fmaxf(fmaxf(redm[0], redm[1]), fmaxf(redm[2], redm[3]));

  float e[8], sum = 0.f;
#pragma unroll
  for (int j = 0; j < 8; ++j) {
    e[j] = __expf(x[j] - m);
    sum += e[j];
  }
#pragma unroll
  for (int off = 32; off; off >>= 1) sum += __shfl_xor(sum, off);
  if ((tid & 63) == 0) reds[tid >> 6] = sum;
  __syncthreads();
  sum = reds[0] + reds[1] + reds[2] + reds[3];
  float inv = 1.f / sum;

  unsigned short o[8];
#pragma unroll
  for (int j = 0; j < 8; ++j) o[j] = f2bf(e[j] * inv);
  ((uint4*)row)[tid] = *(const uint4*)o;  // first 4KB of the 8KB row
}

// ---------------------------------------------------------------------------
extern "C" void kernel_launch(void* const* d_in, const int* in_sizes, int n_in,
                              void* d_out, int out_size, void* d_ws, size_t ws_size,
                              hipStream_t stream) {
  const float* x = (const float*)d_in[0];
  const float* Wq = (const float*)d_in[1];
  const float* Wk = (const float*)d_in[2];
  const float* Wv = (const float*)d_in[3];
  float* out = (float*)d_out;

  unsigned short* xb = (unsigned short*)d_ws;       // 8192x1024 bf16
  unsigned short* Wb = xb + (long)8192 * 1024;      // 3072x1024 bf16 (Wq|Wk|Wv)
  unsigned short* Qr = Wb + (long)3 * 1024 * 1024;  // 8192x1024 bf16
  unsigned short* Kr = Qr + (long)8192 * 1024;
  unsigned short* Vt = Kr + (long)8192 * 1024;      // [b][c][t]
  float* S = (float*)(Vt + (long)8192 * 1024);      // BCH x 2048 x 2048 fp32 (P in place)

  const size_t baseBytes = ((size_t)8192 * 1024 * 2) * 4 + (size_t)3 * 1024 * 1024 * 2;
  int BCH = 4;
  while (BCH > 1 && baseBytes + (size_t)BCH * 2048 * 2048 * 4 > ws_size) BCH >>= 1;

  // 1) casts
  cvt_bf16<<<8192, 256, 0, stream>>>((const float4*)x, (ushort4*)xb, 2097152);
  cvt_bf16<<<1024, 256, 0, stream>>>((const float4*)Wq, (ushort4*)Wb, 262144);
  cvt_bf16<<<1024, 256, 0, stream>>>((const float4*)Wk, (ushort4*)(Wb + (long)1024 * 1024), 262144);
  cvt_bf16<<<1024, 256, 0, stream>>>((const float4*)Wv, (ushort4*)(Wb + (long)2048 * 1024), 262144);

  // 2) fused QKV projection + RoPE (+V transpose)
  gemm_nt<0><<<dim3(24, 64, 1), 256, 0, stream>>>(xb, Wb, nullptr, Qr, Kr, Vt,
                                                  1024, 1024, 0, 1024, 0);

  // 3..5) attention, in batch chunks sized by workspace
  for (int b0 = 0; b0 < 4; b0 += BCH) {
    gemm_nt<1><<<dim3(16, 16, BCH), 256, 0, stream>>>(Qr, Kr, S, nullptr, nullptr, nullptr,
                                                      1024, 1024, 2048, 1024, b0);
    softmax_rows<<<dim3(2048 * BCH), 256, 0, stream>>>(S);
    gemm_nt<2><<<dim3(8, 16, BCH), 256, 0, stream>>>((const unsigned short*)S, Vt, out,
                                                     nullptr, nullptr, nullptr,
                                                     4096, 2048, 1024, 2048, b0);
  }
}